// Round 8
// baseline (93.912 us; speedup 1.0000x reference)
//
#include <hip/hip_runtime.h>

// out = F_amp(MLP(z_i, z_j, sep_xy2)) * (dxy / sep_r2)
// Weights (271 floats) pre-packed into d_ws (9 async d2d copies), staged to
// LDS once per block, read as ds_read_b64 pairs (uniform addr = broadcast,
// LGKM pipe, parallel to VALU). No per-element scalar-memory traffic at all
// (that serial s_load/lgkmcnt-drain stream was the shared ~69us floor of
// R3/R4/R6). Neuron-pair packing + free activation splat via VOP3P op_sel.
// Both elements of the thread's pair interleaved: each weight read feeds 2
// packed FMAs.

typedef float f32x4 __attribute__((ext_vector_type(4)));
typedef float f32x2 __attribute__((ext_vector_type(2)));

// d = splat(a.lo) * w + c   /   d = splat(a.hi) * w + c   (all VGPR)
__device__ __forceinline__ f32x2 pkfma_lo(f32x2 a, f32x2 w, f32x2 c) {
    f32x2 d;
    asm("v_pk_fma_f32 %0, %1, %2, %3 op_sel:[0,0,0] op_sel_hi:[0,1,1]"
        : "=v"(d) : "v"(a), "v"(w), "v"(c));
    return d;
}
__device__ __forceinline__ f32x2 pkfma_hi(f32x2 a, f32x2 w, f32x2 c) {
    f32x2 d;
    asm("v_pk_fma_f32 %0, %1, %2, %3 op_sel:[1,0,0] op_sel_hi:[1,1,1]"
        : "=v"(d) : "v"(a), "v"(w), "v"(c));
    return d;
}

__device__ __forceinline__ f32x2 fma2(f32x2 a, f32x2 b, f32x2 c) {
    return __builtin_elementwise_fma(a, b, c);
}

__device__ __forceinline__ f32x2 lrelu2(f32x2 x) {
    return __builtin_elementwise_max(x, x * 0.1f);   // alpha=0.1
}

__device__ __forceinline__ float tanh_fast(float x) {
    // tanh(x) = 1 - 2/(exp2(x*2log2e)+1)
    float e = __builtin_amdgcn_exp2f(x * 2.8853900817779268f);
    return fmaf(-2.0f, __builtin_amdgcn_rcpf(e + 1.0f), 1.0f);
}

// packed LDS weight layout (float offsets; all pair bases even)
#define OW1 0
#define OB1 30
#define OW2 40
#define OB2 140
#define OW3 150
#define OB3 250
#define OW4 260
#define OB4 270

__global__ void __launch_bounds__(256) fused_mlp_kernel(
    const float* __restrict__ in, const float* __restrict__ wpack,
    float* __restrict__ out, int npairs)
{
    __shared__ float wbuf[272];
    if (threadIdx.x < 68)
        reinterpret_cast<f32x4*>(wbuf)[threadIdx.x] =
            reinterpret_cast<const f32x4*>(wpack)[threadIdx.x];
    __syncthreads();

    int p = blockIdx.x * blockDim.x + threadIdx.x;
    if (p >= npairs) return;

    const f32x2* wb2 = reinterpret_cast<const f32x2*>(wbuf);
#define LP(off) (wb2[(off) >> 1])

    const f32x4* in4 = reinterpret_cast<const f32x4*>(in);
    f32x4 A = in4[3 * p + 0];
    f32x4 B = in4[3 * p + 1];
    f32x4 C = in4[3 * p + 2];

    // element0 = {A0 A1 A2 A3 B0 B1}, element1 = {B2 B3 C0 C1 C2 C3}
    float xs[2][6] = {
        {A[0], A[1], A[2], A[3], B[0], B[1]},
        {B[2], B[3], C[0], C[1], C[2], C[3]}
    };

    // features per element; z packed as {z_i, z_j} and {sep_xy2, -} for op_sel
    float dxe[2], dye[2], inve[2];
    f32x2 zAB[2], zC[2];
    #pragma unroll
    for (int e = 0; e < 2; ++e) {
        float dx = xs[e][3] - xs[e][0];
        float dy = xs[e][4] - xs[e][1];
        float dz = xs[e][5] - xs[e][2];
        float sep_xy2 = fmaf(dx, dx, dy * dy);
        float sep_r2  = fmaf(dz, dz, sep_xy2);
        dxe[e] = dx; dye[e] = dy;
        inve[e] = __builtin_amdgcn_rcpf(sep_r2);
        f32x2 t; t[0] = xs[e][2]; t[1] = xs[e][5];
        zAB[e] = t;
        f32x2 u; u[0] = sep_xy2; u[1] = sep_xy2;
        zC[e] = u;
    }

    // ---- Layer 1: [3]->[10], leaky relu (weights shared by both elements)
    f32x2 h1a[5], h1b[5];
    #pragma unroll
    for (int jp = 0; jp < 5; ++jp) {
        f32x2 bb = LP(OB1 + 2 * jp);
        f32x2 w0 = LP(OW1 + 0  + 2 * jp);
        f32x2 w1 = LP(OW1 + 10 + 2 * jp);
        f32x2 w2 = LP(OW1 + 20 + 2 * jp);
        f32x2 a0 = pkfma_lo(zAB[0], w0, bb);
        f32x2 a1 = pkfma_lo(zAB[1], w0, bb);
        a0 = pkfma_hi(zAB[0], w1, a0);
        a1 = pkfma_hi(zAB[1], w1, a1);
        a0 = pkfma_lo(zC[0], w2, a0);
        a1 = pkfma_lo(zC[1], w2, a1);
        h1a[jp] = lrelu2(a0);
        h1b[jp] = lrelu2(a1);
    }

    // ---- Layer 2: [10]->[10], tanh
    f32x2 a2a[5], a2b[5];
    #pragma unroll
    for (int jp = 0; jp < 5; ++jp) {
        f32x2 bb = LP(OB2 + 2 * jp);
        a2a[jp] = bb; a2b[jp] = bb;
    }
    #pragma unroll
    for (int i = 0; i < 10; ++i) {
        #pragma unroll
        for (int jp = 0; jp < 5; ++jp) {
            f32x2 w = LP(OW2 + i * 10 + 2 * jp);
            if (i & 1) {
                a2a[jp] = pkfma_hi(h1a[i >> 1], w, a2a[jp]);
                a2b[jp] = pkfma_hi(h1b[i >> 1], w, a2b[jp]);
            } else {
                a2a[jp] = pkfma_lo(h1a[i >> 1], w, a2a[jp]);
                a2b[jp] = pkfma_lo(h1b[i >> 1], w, a2b[jp]);
            }
        }
    }
    f32x2 h2a[5], h2b[5];
    #pragma unroll
    for (int jp = 0; jp < 5; ++jp) {
        f32x2 t, u;
        t[0] = tanh_fast(a2a[jp][0]); t[1] = tanh_fast(a2a[jp][1]);
        u[0] = tanh_fast(a2b[jp][0]); u[1] = tanh_fast(a2b[jp][1]);
        h2a[jp] = t; h2b[jp] = u;
    }

    // ---- Layer 3: [10]->[10], leaky relu
    f32x2 a3a[5], a3b[5];
    #pragma unroll
    for (int jp = 0; jp < 5; ++jp) {
        f32x2 bb = LP(OB3 + 2 * jp);
        a3a[jp] = bb; a3b[jp] = bb;
    }
    #pragma unroll
    for (int i = 0; i < 10; ++i) {
        #pragma unroll
        for (int jp = 0; jp < 5; ++jp) {
            f32x2 w = LP(OW3 + i * 10 + 2 * jp);
            if (i & 1) {
                a3a[jp] = pkfma_hi(h2a[i >> 1], w, a3a[jp]);
                a3b[jp] = pkfma_hi(h2b[i >> 1], w, a3b[jp]);
            } else {
                a3a[jp] = pkfma_lo(h2a[i >> 1], w, a3a[jp]);
                a3b[jp] = pkfma_lo(h2b[i >> 1], w, a3b[jp]);
            }
        }
    }
    f32x2 h3a[5], h3b[5];
    #pragma unroll
    for (int jp = 0; jp < 5; ++jp) {
        h3a[jp] = lrelu2(a3a[jp]);
        h3b[jp] = lrelu2(a3b[jp]);
    }

    // ---- Layer 4: [10]->[1]; full pk dot, weight pairs from LDS
    f32x2 f0; f0[0] = wbuf[OB4]; f0[1] = 0.0f;
    f32x2 f1 = f0;
    #pragma unroll
    for (int ip = 0; ip < 5; ++ip) {
        f32x2 w = LP(OW4 + 2 * ip);
        f0 = fma2(h3a[ip], w, f0);
        f1 = fma2(h3b[ip], w, f1);
    }
    float fa = f0[0] + f0[1];
    float fb = f1[0] + f1[1];

    float s0 = fa * inve[0];
    float s1 = fb * inve[1];

    f32x4 o;
    o[0] = s0 * dxe[0]; o[1] = s0 * dye[0];
    o[2] = s1 * dxe[1]; o[3] = s1 * dye[1];
    reinterpret_cast<f32x4*>(out)[p] = o;
#undef LP
}

extern "C" void kernel_launch(void* const* d_in, const int* in_sizes, int n_in,
                              void* d_out, int out_size, void* d_ws, size_t ws_size,
                              hipStream_t stream) {
    const float* in = (const float*)d_in[0];
    float* wsf = (float*)d_ws;

    // pack weights contiguously into d_ws: W1 b1 W2 b2 W3 b3 W4 b4
    static const int offs[8] = {OW1, OB1, OW2, OB2, OW3, OB3, OW4, OB4};
    static const int cnts[8] = {30, 10, 100, 10, 100, 10, 10, 1};
    for (int t = 0; t < 8; ++t) {
        hipMemcpyAsync(wsf + offs[t], d_in[1 + t], cnts[t] * sizeof(float),
                       hipMemcpyDeviceToDevice, stream);
    }

    float* out = (float*)d_out;
    int npairs = out_size / 4;          // 2 elements (4 output floats) per thread
    int blocks = (npairs + 255) / 256;
    fused_mlp_kernel<<<blocks, 256, 0, stream>>>(in, wsf, out, npairs);
}